// Round 1
// baseline (23.886 us; speedup 1.0000x reference)
//
#include <hip/hip_runtime.h>

#define D 128
#define MTILE 64
#define WPITCH 68  // weT pitch in floats: 16B-aligned, (4x+lane)%32 banks -> conflict-free

// Prep: blocks 0..127 compute W2[x][j] = sum_y (sum_z T[x,y,z]*tv[z]) * op_w[j,y]
//       block 128 computes bias2[j] = sum_y (sum_z B[y,z]*tv[z]) * op_w[j,y] + op_b[j]
__global__ __launch_bounds__(128) void prep_kernel(
    const float* __restrict__ T, const float* __restrict__ Bm,
    const float* __restrict__ tv, const float* __restrict__ op_w,
    const float* __restrict__ op_b, float* __restrict__ W2,
    float* __restrict__ bias2)
{
    __shared__ float m_s[D];
    const int x = blockIdx.x;
    const int t = threadIdx.x;  // 0..127
    const float* src = (x < D) ? (T + (size_t)x * D * D) : Bm;
    const float4* row = (const float4*)(src + t * D);
    const float4* tv4 = (const float4*)tv;
    float acc = 0.f;
#pragma unroll 8
    for (int k = 0; k < D / 4; ++k) {
        float4 a = row[k];
        float4 b = tv4[k];
        acc += a.x * b.x + a.y * b.y + a.z * b.z + a.w * b.w;
    }
    m_s[t] = acc;
    __syncthreads();
    // thread j = t: dot(m, op_w[j,:])
    const float4* wrow = (const float4*)(op_w + t * D);
    const float4* m4 = (const float4*)m_s;
    float acc2 = 0.f;
#pragma unroll 8
    for (int k = 0; k < D / 4; ++k) {
        float4 a = wrow[k];
        float4 b = m4[k];
        acc2 += a.x * b.x + a.y * b.y + a.z * b.z + a.w * b.w;
    }
    if (x < D) W2[x * D + t] = acc2;
    else       bias2[t] = acc2 + op_b[t];
}

// Main: out[b,j] = sum_x we[idx[b],x] * W2[x,j] + bias2[j]
// 256 threads/block, 64-row M-tile, each thread computes 4 rows x 8 cols.
__global__ __launch_bounds__(256) void main_gemm(
    const int* __restrict__ idx, const float* __restrict__ w_embed,
    const float* __restrict__ W2, const float* __restrict__ bias2,
    float* __restrict__ out)
{
    __shared__ float weT[D][WPITCH];   // [x][r] transposed embeddings
    __shared__ float W2s[D * D];       // [x][j] row-major
    __shared__ float bias_s[D];

    const int t = threadIdx.x;
    const int b0 = blockIdx.x * MTILE;

    // stage gathered embeddings, transposed: thread t -> row r=t%64, x-quarter q=t/64
    {
        const int r = t & 63;
        const int q = t >> 6;
        const int g = idx[b0 + r];
        const float4* src = (const float4*)(w_embed + (size_t)g * D + q * 32);
#pragma unroll
        for (int k = 0; k < 8; ++k) {
            float4 v = src[k];
            const int x = q * 32 + k * 4;
            weT[x + 0][r] = v.x;
            weT[x + 1][r] = v.y;
            weT[x + 2][r] = v.z;
            weT[x + 3][r] = v.w;
        }
    }
    // stage W2 (64 KB), coalesced float4
    {
        const float4* s = (const float4*)W2;
        float4* dst = (float4*)W2s;
#pragma unroll
        for (int i = 0; i < (D * D / 4) / 256; ++i)  // 16 iters
            dst[t + i * 256] = s[t + i * 256];
    }
    if (t < D / 4) ((float4*)bias_s)[t] = ((const float4*)bias2)[t];
    __syncthreads();

    const int tx = t & 15;   // col group: c0 = tx*8
    const int ty = t >> 4;   // row group: r0 = ty*4
    const int c0 = tx * 8;
    const int r0 = ty * 4;

    float acc[4][8];
#pragma unroll
    for (int i = 0; i < 4; ++i)
#pragma unroll
        for (int j = 0; j < 8; ++j) acc[i][j] = 0.f;

#pragma unroll 4
    for (int x = 0; x < D; ++x) {
        float4 a  = *(const float4*)&weT[x][r0];
        float4 bA = *(const float4*)&W2s[x * D + c0];
        float4 bB = *(const float4*)&W2s[x * D + c0 + 4];
        const float av[4] = {a.x, a.y, a.z, a.w};
        const float bv[8] = {bA.x, bA.y, bA.z, bA.w, bB.x, bB.y, bB.z, bB.w};
#pragma unroll
        for (int i = 0; i < 4; ++i)
#pragma unroll
            for (int j = 0; j < 8; ++j)
                acc[i][j] += av[i] * bv[j];
    }

    float4 bb0 = *(const float4*)&bias_s[c0];
    float4 bb1 = *(const float4*)&bias_s[c0 + 4];
    const float bb[8] = {bb0.x, bb0.y, bb0.z, bb0.w, bb1.x, bb1.y, bb1.z, bb1.w};
#pragma unroll
    for (int i = 0; i < 4; ++i) {
        float* o = out + (size_t)(b0 + r0 + i) * D + c0;
        float4 o0 = make_float4(acc[i][0] + bb[0], acc[i][1] + bb[1],
                                acc[i][2] + bb[2], acc[i][3] + bb[3]);
        float4 o1 = make_float4(acc[i][4] + bb[4], acc[i][5] + bb[5],
                                acc[i][6] + bb[6], acc[i][7] + bb[7]);
        *(float4*)o = o0;
        *(float4*)(o + 4) = o1;
    }
}

extern "C" void kernel_launch(void* const* d_in, const int* in_sizes, int n_in,
                              void* d_out, int out_size, void* d_ws, size_t ws_size,
                              hipStream_t stream) {
    const int*   idx     = (const int*)d_in[0];
    const float* w_embed = (const float*)d_in[1];
    const float* T       = (const float*)d_in[2];
    const float* Bm      = (const float*)d_in[3];
    const float* tv      = (const float*)d_in[4];
    const float* op_w    = (const float*)d_in[5];
    const float* op_b    = (const float*)d_in[6];
    float* out = (float*)d_out;

    float* W2    = (float*)d_ws;        // D*D floats
    float* bias2 = W2 + D * D;          // D floats

    prep_kernel<<<D + 1, D, 0, stream>>>(T, Bm, tv, op_w, op_b, W2, bias2);
    main_gemm<<<16384 / MTILE, 256, 0, stream>>>(idx, w_embed, W2, bias2, out);
}

// Round 2
// 22.376 us; speedup vs baseline: 1.0675x; 1.0675x over previous
//
#include <hip/hip_runtime.h>

#define D 128
#define BATCH 16384

typedef float f32x4 __attribute__((ext_vector_type(4)));
typedef short bh8 __attribute__((ext_vector_type(8)));

__device__ __forceinline__ unsigned short f2bf(float f) {
    unsigned u = __float_as_uint(f);
    u += 0x7FFFu + ((u >> 16) & 1u);   // round-to-nearest-even
    return (unsigned short)(u >> 16);
}

// Stage 1: m[R] = dot(row R of [T (16384 rows); B (128 rows)], tv)
// 8 rows/block, 32 lanes per row (coalesced float4), shuffle-reduce.
__global__ __launch_bounds__(256) void stage1(
    const float* __restrict__ T, const float* __restrict__ Bm,
    const float* __restrict__ tv, float* __restrict__ m)
{
    const int t = threadIdx.x;
    const int lr = t >> 5;           // 0..7 local row
    const int c4 = t & 31;           // float4 chunk within row
    const int R = blockIdx.x * 8 + lr;
    const float* src = (R < BATCH) ? (T + (size_t)R * D)
                                   : (Bm + (size_t)(R - BATCH) * D);
    f32x4 v = *(const f32x4*)(src + c4 * 4);
    f32x4 w = *(const f32x4*)(tv + c4 * 4);
    float p = v[0]*w[0] + v[1]*w[1] + v[2]*w[2] + v[3]*w[3];
#pragma unroll
    for (int s = 16; s >= 1; s >>= 1) p += __shfl_xor(p, s, 32);
    if (c4 == 0) m[R] = p;
}

// Stage 2: block j: W2T[j][x] = bf16( sum_y m[x,y] * op_w[j,y] )  (col-major W2)
//          bias2[j] = sum_y mB[y] * op_w[j,y] + op_b[j]
__global__ __launch_bounds__(128) void stage2(
    const float* __restrict__ m, const float* __restrict__ op_w,
    const float* __restrict__ op_b, unsigned short* __restrict__ W2T,
    float* __restrict__ bias2)
{
    __shared__ float wj[D];
    __shared__ float red[D];
    const int j = blockIdx.x;
    const int x = threadIdx.x;
    if (x < D / 4) ((f32x4*)wj)[x] = ((const f32x4*)(op_w + (size_t)j * D))[x];
    __syncthreads();
    const float* mr = m + (size_t)x * D;
    float acc = 0.f;
#pragma unroll
    for (int k = 0; k < D / 4; ++k) {
        f32x4 a = ((const f32x4*)mr)[k];
        f32x4 b = ((const f32x4*)wj)[k];
        acc += a[0]*b[0] + a[1]*b[1] + a[2]*b[2] + a[3]*b[3];
    }
    W2T[(size_t)j * D + x] = f2bf(acc);
    red[x] = m[(size_t)BATCH * 1 * 0 + 16384 + x] * wj[x];  // mB[y] = m[16384+y]
    __syncthreads();
    if (x == 0) {
        float s = 0.f;
        for (int y = 0; y < D; ++y) s += red[y];
        bias2[j] = s + op_b[j];
    }
}

// Main: out[b,j] = sum_x we[idx[b],x] * W2[x,j] + bias2[j] via bf16 MFMA.
// One wave per 16-row tile. A: gather global->reg->bf16. B: from L2-resident W2T.
// A-frag: row=l&15, k=(l>>4)*8+i.  B-frag: col=l&15, k=(l>>4)*8+i (W2T is col-major).
// D-frag: col=l&15, row=(l>>4)*4+r.
__global__ __launch_bounds__(256) void main_mfma(
    const int* __restrict__ idx, const float* __restrict__ we,
    const unsigned short* __restrict__ W2T, const float* __restrict__ bias2,
    float* __restrict__ out)
{
    const int t = threadIdx.x;
    const int wv = t >> 6;
    const int l = t & 63;
    const int l15 = l & 15, lg = l >> 4;
    const int b0 = (blockIdx.x * 4 + wv) * 16;

    const int g = idx[b0 + l15];
    const float* arow = we + (size_t)g * D;

    f32x4 acc[8];
#pragma unroll
    for (int c = 0; c < 8; ++c) acc[c] = (f32x4){0.f, 0.f, 0.f, 0.f};

#pragma unroll
    for (int s = 0; s < 4; ++s) {
        f32x4 a0 = *(const f32x4*)(arow + s * 32 + lg * 8);
        f32x4 a1 = *(const f32x4*)(arow + s * 32 + lg * 8 + 4);
        bh8 af;
        af[0] = (short)f2bf(a0[0]); af[1] = (short)f2bf(a0[1]);
        af[2] = (short)f2bf(a0[2]); af[3] = (short)f2bf(a0[3]);
        af[4] = (short)f2bf(a1[0]); af[5] = (short)f2bf(a1[1]);
        af[6] = (short)f2bf(a1[2]); af[7] = (short)f2bf(a1[3]);
#pragma unroll
        for (int c = 0; c < 8; ++c) {
            bh8 bf = *(const bh8*)(W2T + (size_t)(c * 16 + l15) * D + s * 32 + lg * 8);
            acc[c] = __builtin_amdgcn_mfma_f32_16x16x32_bf16(af, bf, acc[c], 0, 0, 0);
        }
    }

#pragma unroll
    for (int c = 0; c < 8; ++c) {
        float bv = bias2[c * 16 + l15];
#pragma unroll
        for (int r = 0; r < 4; ++r) {
            out[(size_t)(b0 + lg * 4 + r) * D + c * 16 + l15] = acc[c][r] + bv;
        }
    }
}

extern "C" void kernel_launch(void* const* d_in, const int* in_sizes, int n_in,
                              void* d_out, int out_size, void* d_ws, size_t ws_size,
                              hipStream_t stream) {
    const int*   idx     = (const int*)d_in[0];
    const float* w_embed = (const float*)d_in[1];
    const float* T       = (const float*)d_in[2];
    const float* Bm      = (const float*)d_in[3];
    const float* tv      = (const float*)d_in[4];
    const float* op_w    = (const float*)d_in[5];
    const float* op_b    = (const float*)d_in[6];
    float* out = (float*)d_out;

    // ws layout: m[16512] f32 | W2T[128*128] bf16 | bias2[128] f32
    float* m = (float*)d_ws;                       // 66048 B
    unsigned short* W2T = (unsigned short*)((char*)d_ws + 66048);  // 32768 B
    float* bias2 = (float*)((char*)d_ws + 66048 + 32768);

    stage1<<<(BATCH + D + 7) / 8, 256, 0, stream>>>(T, Bm, tv, m);
    stage2<<<D, D, 0, stream>>>(m, op_w, op_b, W2T, bias2);
    main_mfma<<<BATCH / 64, 256, 0, stream>>>(idx, w_embed, W2T, bias2, out);
}